// Round 5
// baseline (89.065 us; speedup 1.0000x reference)
//
#include <hip/hip_runtime.h>
#include <math.h>

// Problem dims (fixed by setup_inputs): B=16, Cin=Cout=64, L=65536, M=512, Lh=32769
#define B_   16
#define CIN  64
#define COUT 64
#define L_   65536
#define M_   512
#define LH_  32769

#define FILL_NBLK  2048
#define FILL_NTHR  (FILL_NBLK * 256)        // 524288
#define N4         ((B_ * COUT * LH_) / 4)  // 8388864 float4s = whole output

// ---------------------------------------------------------------------------
// Kernel A: compute cols [0,512). Runs FIRST, with no store flood in flight:
// loads see cold store queues -> L2-hit latencies, fully pipelined.
// Thread tile: 2b x 2o at one m; 131072 threads = 512 blocks.
//   m2 = (512 - m) % 512
//   out[b,o,m] = 0.5*c2[m] * sum_i( x[b,i,m]*c1[m]*(w[i,o,m]+w[i,o,m2])
//                                 + x[b,i,m2]*c1[m2]*(w[i,o,m]-w[i,o,m2]) )
//   c1[m] = cos(2pi m/L) - sin(2pi m/L); c2[m] = (cos(2pi m/Lh)-sin(2pi m/Lh))/Cin
// ---------------------------------------------------------------------------
__global__ __launch_bounds__(256) void spectral_compute(
    const float* __restrict__ x, const float* __restrict__ w, float* __restrict__ out)
{
    const int ctid = (int)blockIdx.x * 256 + (int)threadIdx.x;  // 0..131071
    const int m  = ctid & 511;              // lane-contiguous -> coalesced
    const int op = (ctid >> 9) & 31;        // o pair
    const int bp = ctid >> 14;              // 0..7, b pair
    const int o0 = op * 2;
    const int b0 = bp * 2;
    const int m2 = (M_ - m) & (M_ - 1);

    const float TWO_PI = 6.28318530717958647692f;
    const float t1  = TWO_PI * (float)m  / (float)L_;
    const float t1n = TWO_PI * (float)m2 / (float)L_;
    const float t2  = TWO_PI * (float)m  / (float)LH_;
    const float c1m = cosf(t1)  - sinf(t1);
    const float c1n = cosf(t1n) - sinf(t1n);
    const float c2  = (cosf(t2) - sinf(t2)) * (0.5f / (float)CIN);

    float a00 = 0.f, a01 = 0.f, a10 = 0.f, a11 = 0.f;

    const float* x0 = x + (size_t)b0 * CIN * L_;
    const float* x1 = x0 + (size_t)CIN * L_;

    #pragma unroll 4
    for (int i = 0; i < CIN; ++i) {
        const size_t ro = (size_t)i * L_;
        const float xm0 = x0[ro + m]  * c1m;
        const float xn0 = x0[ro + m2] * c1n;
        const float xm1 = x1[ro + m]  * c1m;
        const float xn1 = x1[ro + m2] * c1n;

        const float* wr = w + (size_t)(i * COUT + o0) * M_;
        const float wmA = wr[m],       wnA = wr[m2];
        const float wmB = wr[M_ + m],  wnB = wr[M_ + m2];
        const float wsA = wmA + wnA, wdA = wmA - wnA;
        const float wsB = wmB + wnB, wdB = wmB - wnB;

        a00 += xm0 * wsA + xn0 * wdA;
        a01 += xm0 * wsB + xn0 * wdB;
        a10 += xm1 * wsA + xn1 * wdA;
        a11 += xm1 * wsB + xn1 * wdB;
    }

    out[(size_t)((b0 + 0) * COUT + o0 + 0) * LH_ + m] = c2 * a00;
    out[(size_t)((b0 + 0) * COUT + o0 + 1) * LH_ + m] = c2 * a01;
    out[(size_t)((b0 + 1) * COUT + o0 + 0) * LH_ + m] = c2 * a10;
    out[(size_t)((b0 + 1) * COUT + o0 + 1) * LH_ + m] = c2 * a11;
}

// ---------------------------------------------------------------------------
// Kernel B: zero-fill output cols >= 512 (132 MB). Pure store-bound.
// Aligned float4 fast path; per-element fallback at row boundaries.
// Disjoint from kernel A's stores (col<512) -> order-independent.
// ---------------------------------------------------------------------------
__global__ __launch_bounds__(256) void spectral_fill(float* __restrict__ out)
{
    const int tid = (int)blockIdx.x * 256 + (int)threadIdx.x;
    for (int j = tid; j < N4; j += FILL_NTHR) {
        const unsigned flat = (unsigned)j * 4u;
        const unsigned row  = flat / (unsigned)LH_;   // magic-mul, const divisor
        const unsigned col  = flat - row * (unsigned)LH_;
        if (col >= (unsigned)M_ && col <= (unsigned)(LH_ - 4)) {
            const float4 z = {0.f, 0.f, 0.f, 0.f};
            reinterpret_cast<float4*>(out)[j] = z;
        } else {
            #pragma unroll
            for (int e = 0; e < 4; ++e) {
                const unsigned f  = flat + (unsigned)e;
                const unsigned r2 = f / (unsigned)LH_;
                const unsigned c2_ = f - r2 * (unsigned)LH_;
                if (c2_ >= (unsigned)M_) out[f] = 0.f;
            }
        }
    }
}

extern "C" void kernel_launch(void* const* d_in, const int* in_sizes, int n_in,
                              void* d_out, int out_size, void* d_ws, size_t ws_size,
                              hipStream_t stream) {
    const float* x = (const float*)d_in[0];   // (16, 64, 65536) f32
    const float* w = (const float*)d_in[1];   // (64, 64, 512)   f32
    float* out = (float*)d_out;               // (16, 64, 32769) f32

    spectral_compute<<<512, 256, 0, stream>>>(x, w, out);
    spectral_fill<<<FILL_NBLK, 256, 0, stream>>>(out);
}

// Round 6
// 69.233 us; speedup vs baseline: 1.2865x; 1.2865x over previous
//
#include <hip/hip_runtime.h>
#include <math.h>

// Problem dims (fixed by setup_inputs): B=16, Cin=Cout=64, L=65536, M=512, Lh=32769
#define B_   16
#define CIN  64
#define COUT 64
#define L_   65536
#define M_   512
#define LH_  32769

#define NBLK     2048
#define NTHREADS (NBLK * 256)              // 524288
#define N4       ((B_ * COUT * LH_) / 4)   // 8388864 float4s = whole output

typedef float f4 __attribute__((ext_vector_type(4)));  // clang-native for nt builtins

// ---------------------------------------------------------------------------
// Fused kernel (R2 structure, proven fastest ordering):
//  Part 1 (all waves): zero-fill cols >= 512 (132 MB) with NON-TEMPORAL
//    stores — keeps x/w resident in L2/L3 across graph replays so part 2's
//    loads are cache hits, and avoids write-allocate pollution.
//  Part 2 (wave 0 of each block, runs after its fill quota): compute
//    cols [0,512). 2048 waves (8/CU), thread tile 2b x 2o at one m:
//    8 loads / 4 outputs, ws/wd shared across the b-pair.
//  Stores disjoint (col>=512 vs col<512) -> no race.
//
//   m2 = (512 - m) % 512
//   out[b,o,m] = 0.5*c2[m] * sum_i( x[b,i,m]*c1[m]*(w[i,o,m]+w[i,o,m2])
//                                 + x[b,i,m2]*c1[m2]*(w[i,o,m]-w[i,o,m2]) )
//   c1[m] = cos(2pi m/L) - sin(2pi m/L); c2[m] = (cos(2pi m/Lh)-sin(2pi m/Lh))/Cin
// ---------------------------------------------------------------------------
__global__ __launch_bounds__(256) void fused_spectral(
    const float* __restrict__ x, const float* __restrict__ w, float* __restrict__ out)
{
    const int tid = (int)blockIdx.x * 256 + (int)threadIdx.x;

    // ---- Part 1: streaming zero-fill of the col>=512 region (non-temporal)
    for (int j = tid; j < N4; j += NTHREADS) {
        const unsigned flat = (unsigned)j * 4u;
        const unsigned row  = flat / (unsigned)LH_;   // magic-mul, const divisor
        const unsigned col  = flat - row * (unsigned)LH_;
        if (col >= (unsigned)M_ && col <= (unsigned)(LH_ - 4)) {
            const f4 z = {0.f, 0.f, 0.f, 0.f};
            __builtin_nontemporal_store(z, reinterpret_cast<f4*>(out) + j);
        } else {
            #pragma unroll
            for (int e = 0; e < 4; ++e) {
                const unsigned f  = flat + (unsigned)e;
                const unsigned r2 = f / (unsigned)LH_;
                const unsigned c2_ = f - r2 * (unsigned)LH_;
                if (c2_ >= (unsigned)M_) __builtin_nontemporal_store(0.f, out + f);
            }
        }
    }

    // ---- Part 2: compute region — wave 0 of each block, after its fill quota
    if (threadIdx.x >= 64) return;
    const int cw   = (int)blockIdx.x;            // 0..2047
    const int lane = (int)threadIdx.x;
    const int m  = ((cw & 7) << 6) + lane;       // 0..511, lane-contiguous
    const int o0 = ((cw >> 3) & 31) * 2;         // o pair
    const int b0 = (cw >> 8) * 2;                // b pair
    const int m2 = (M_ - m) & (M_ - 1);

    const float TWO_PI = 6.28318530717958647692f;
    const float t1  = TWO_PI * (float)m  / (float)L_;
    const float t1n = TWO_PI * (float)m2 / (float)L_;
    const float t2  = TWO_PI * (float)m  / (float)LH_;
    const float c1m = cosf(t1)  - sinf(t1);
    const float c1n = cosf(t1n) - sinf(t1n);
    const float c2  = (cosf(t2) - sinf(t2)) * (0.5f / (float)CIN);

    float a00 = 0.f, a01 = 0.f, a10 = 0.f, a11 = 0.f;

    const float* xA = x + (size_t)b0 * CIN * L_;
    const float* xB = xA + (size_t)CIN * L_;

    #pragma unroll 4
    for (int i = 0; i < CIN; ++i) {
        const size_t ro = (size_t)i * L_;
        const float xmA = xA[ro + m]  * c1m;
        const float xnA = xA[ro + m2] * c1n;
        const float xmB = xB[ro + m]  * c1m;
        const float xnB = xB[ro + m2] * c1n;

        const float* wr = w + (size_t)(i * COUT + o0) * M_;
        const float wm0 = wr[m],      wn0 = wr[m2];
        const float wm1 = wr[M_ + m], wn1 = wr[M_ + m2];
        const float ws0 = wm0 + wn0, wd0 = wm0 - wn0;
        const float ws1 = wm1 + wn1, wd1 = wm1 - wn1;

        a00 += xmA * ws0 + xnA * wd0;
        a01 += xmA * ws1 + xnA * wd1;
        a10 += xmB * ws0 + xnB * wd0;
        a11 += xmB * ws1 + xnB * wd1;
    }

    out[(size_t)((b0 + 0) * COUT + o0 + 0) * LH_ + m] = c2 * a00;
    out[(size_t)((b0 + 0) * COUT + o0 + 1) * LH_ + m] = c2 * a01;
    out[(size_t)((b0 + 1) * COUT + o0 + 0) * LH_ + m] = c2 * a10;
    out[(size_t)((b0 + 1) * COUT + o0 + 1) * LH_ + m] = c2 * a11;
}

extern "C" void kernel_launch(void* const* d_in, const int* in_sizes, int n_in,
                              void* d_out, int out_size, void* d_ws, size_t ws_size,
                              hipStream_t stream) {
    const float* x = (const float*)d_in[0];   // (16, 64, 65536) f32
    const float* w = (const float*)d_in[1];   // (64, 64, 512)   f32
    float* out = (float*)d_out;               // (16, 64, 32769) f32

    fused_spectral<<<NBLK, 256, 0, stream>>>(x, w, out);
}

// Round 7
// 38.930 us; speedup vs baseline: 2.2878x; 1.7784x over previous
//
#include <hip/hip_runtime.h>
#include <math.h>

// Problem dims (fixed by setup_inputs): B=16, Cin=Cout=64, L=65536, M=512, Lh=32769
#define B_   16
#define CIN  64
#define COUT 64
#define L_   65536
#define M_   512
#define LH_  32769

#define NBLK     2048
#define NTHREADS (NBLK * 256)              // 524288
#define N4       ((B_ * COUT * LH_) / 4)   // 8388864 float4s = whole output

// ---------------------------------------------------------------------------
// Fused kernel, COMPUTE-FIRST (loads run before any store flood exists):
//  Phase A (all 4 waves of every block): compute cols [0,512).
//    Block cw owns a 2b x 2o x 64m output tile (256 outputs).
//    i-split: wave v accumulates i in [16v, 16v+16) -> each wave only 16
//    latency windows; 8192 waves load concurrently = full-machine MLP.
//    LDS reduce (4 KB) + wave 0 applies c2 scale and stores.
//  Phase B (all threads): zero-fill cols >= 512 (132 MB) with REGULAR
//    stores — output fits in 256 MB L3 (writeback absorbs; nt-stores
//    regressed in R6).
//  Stores disjoint (col<512 vs col>=512) -> no race.
//
//   m2 = (512 - m) % 512
//   out[b,o,m] = 0.5*c2[m] * sum_i( x[b,i,m]*c1[m]*(w[i,o,m]+w[i,o,m2])
//                                 + x[b,i,m2]*c1[m2]*(w[i,o,m]-w[i,o,m2]) )
//   c1[m] = cos(2pi m/L) - sin(2pi m/L); c2[m] = (cos(2pi m/Lh)-sin(2pi m/Lh))/Cin
// ---------------------------------------------------------------------------
__global__ __launch_bounds__(256) void fused_spectral(
    const float* __restrict__ x, const float* __restrict__ w, float* __restrict__ out)
{
    __shared__ float4 red[256];     // [wave][lane] partial accumulators

    const int wv   = (int)threadIdx.x >> 6;
    const int lane = (int)threadIdx.x & 63;
    const int cw   = (int)blockIdx.x;            // 0..2047

    // ---- Phase A: compute, 4-way i-split ----
    const int m  = ((cw & 7) << 6) + lane;       // 0..511, lane-contiguous
    const int o0 = ((cw >> 3) & 31) * 2;         // o pair
    const int b0 = (cw >> 8) * 2;                // b pair
    const int m2 = (M_ - m) & (M_ - 1);

    float a00 = 0.f, a01 = 0.f, a10 = 0.f, a11 = 0.f;
    {
        const float TWO_PI = 6.28318530717958647692f;
        const float t1  = TWO_PI * (float)m  / (float)L_;
        const float t1n = TWO_PI * (float)m2 / (float)L_;
        const float c1m = cosf(t1)  - sinf(t1);
        const float c1n = cosf(t1n) - sinf(t1n);

        const float* xA = x + (size_t)b0 * CIN * L_;
        const float* xB = xA + (size_t)CIN * L_;
        const int i0 = wv * 16;

        #pragma unroll 4
        for (int ii = 0; ii < 16; ++ii) {
            const size_t ro = (size_t)(i0 + ii) * L_;
            const float xmA = xA[ro + m]  * c1m;
            const float xnA = xA[ro + m2] * c1n;
            const float xmB = xB[ro + m]  * c1m;
            const float xnB = xB[ro + m2] * c1n;

            const float* wr = w + (size_t)((i0 + ii) * COUT + o0) * M_;
            const float wm0 = wr[m],      wn0 = wr[m2];
            const float wm1 = wr[M_ + m], wn1 = wr[M_ + m2];
            const float ws0 = wm0 + wn0, wd0 = wm0 - wn0;
            const float ws1 = wm1 + wn1, wd1 = wm1 - wn1;

            a00 += xmA * ws0 + xnA * wd0;
            a01 += xmA * ws1 + xnA * wd1;
            a10 += xmB * ws0 + xnB * wd0;
            a11 += xmB * ws1 + xnB * wd1;
        }
    }

    red[threadIdx.x] = make_float4(a00, a01, a10, a11);
    __syncthreads();

    if (wv == 0) {
        const float4 r0 = red[lane];
        const float4 r1 = red[64 + lane];
        const float4 r2 = red[128 + lane];
        const float4 r3 = red[192 + lane];
        const float TWO_PI = 6.28318530717958647692f;
        const float t2 = TWO_PI * (float)m / (float)LH_;
        const float c2 = (cosf(t2) - sinf(t2)) * (0.5f / (float)CIN);
        out[(size_t)((b0 + 0) * COUT + o0 + 0) * LH_ + m] = c2 * (r0.x + r1.x + r2.x + r3.x);
        out[(size_t)((b0 + 0) * COUT + o0 + 1) * LH_ + m] = c2 * (r0.y + r1.y + r2.y + r3.y);
        out[(size_t)((b0 + 1) * COUT + o0 + 0) * LH_ + m] = c2 * (r0.z + r1.z + r2.z + r3.z);
        out[(size_t)((b0 + 1) * COUT + o0 + 1) * LH_ + m] = c2 * (r0.w + r1.w + r2.w + r3.w);
    }

    // ---- Phase B: streaming zero-fill of the col>=512 region ----
    const int tid = cw * 256 + (int)threadIdx.x;
    for (int j = tid; j < N4; j += NTHREADS) {
        const unsigned flat = (unsigned)j * 4u;
        const unsigned row  = flat / (unsigned)LH_;   // magic-mul, const divisor
        const unsigned col  = flat - row * (unsigned)LH_;
        if (col >= (unsigned)M_ && col <= (unsigned)(LH_ - 4)) {
            const float4 z = {0.f, 0.f, 0.f, 0.f};
            reinterpret_cast<float4*>(out)[j] = z;
        } else {
            #pragma unroll
            for (int e = 0; e < 4; ++e) {
                const unsigned f   = flat + (unsigned)e;
                const unsigned r2_ = f / (unsigned)LH_;
                const unsigned c2_ = f - r2_ * (unsigned)LH_;
                if (c2_ >= (unsigned)M_) out[f] = 0.f;
            }
        }
    }
}

extern "C" void kernel_launch(void* const* d_in, const int* in_sizes, int n_in,
                              void* d_out, int out_size, void* d_ws, size_t ws_size,
                              hipStream_t stream) {
    const float* x = (const float*)d_in[0];   // (16, 64, 65536) f32
    const float* w = (const float*)d_in[1];   // (64, 64, 512)   f32
    float* out = (float*)d_out;               // (16, 64, 32769) f32

    fused_spectral<<<NBLK, 256, 0, stream>>>(x, w, out);
}